// Round 1
// baseline (7604.459 us; speedup 1.0000x reference)
//
#include <hip/hip_runtime.h>
#include <math.h>

#define NS 4
#define NB 32
#define CIN 128
#define NCOUT 256
#define HWN 256
#define ND 1152
#define NK 8192   // NB*HWN
static const size_t D2 = (size_t)ND * ND;

// ---------------- small prep kernels ----------------

__global__ void k_sqrtp(const float* __restrict__ lp, float* __restrict__ sp) {
  int b = threadIdx.x;
  if (b < NB) sp[b] = expf(0.5f * lp[b]);
}

// P[s][d][b*256+p] = sqrtp[b] * X[s][b][c][y+ky-1][x+kx-1] (zero padded), d=(c*3+ky)*3+kx
__global__ __launch_bounds__(256) void k_patches(const float* __restrict__ X,
                                                 const float* __restrict__ sp,
                                                 float* __restrict__ P) {
  int d = blockIdx.x, s = blockIdx.y, p = threadIdx.x;
  int c = d / 9, r = d % 9, ky = r / 3, kx = r % 3;
  int yy = (p >> 4) + ky - 1, xx = (p & 15) + kx - 1;
  bool ok = (yy >= 0 && yy < 16 && xx >= 0 && xx < 16);
  int xoff = yy * 16 + xx;
  float* Pd = P + ((size_t)s * ND + d) * NK + p;
  for (int b = 0; b < NB; ++b) {
    float v = 0.f;
    if (ok) v = X[((size_t)(s * NB + b) * CIN + c) * HWN + xoff] * sp[b];
    Pd[b * HWN] = v;
  }
}

// Yt[b*256+p][c] = sqrtp[b]*u[b][c][p]   (transpose via LDS)
__global__ __launch_bounds__(256) void k_yt(const float* __restrict__ u,
                                            const float* __restrict__ sp,
                                            float* __restrict__ Yt) {
  __shared__ float t[32][33];
  int c0 = blockIdx.x * 32, p0 = blockIdx.y * 32, b = blockIdx.z;
  int tx = threadIdx.x & 31, ty = threadIdx.x >> 5;  // 32 x 8
  float s = sp[b];
#pragma unroll
  for (int k = 0; k < 4; ++k) {
    int c = c0 + ty + 8 * k;
    t[ty + 8 * k][tx] = u[((size_t)b * NCOUT + c) * HWN + p0 + tx] * s;
  }
  __syncthreads();
#pragma unroll
  for (int k = 0; k < 4; ++k) {
    int p = p0 + ty + 8 * k;
    Yt[((size_t)b * HWN + p) * NCOUT + c0 + tx] = t[tx][ty + 8 * k];
  }
}

// ---------------- fused XLX (syrk, lower) + XLY GEMM ----------------
// grid (22, 9, 4): jt<18 -> XLX col-tile (64), jt>=18 -> XLY col-tile (64 of COUT)
// tile 128(i) x 64(j), TK=32, 256 thr, 8x4 micro
__global__ __launch_bounds__(256) void k_gemm(const float* __restrict__ P,
                                              const float* __restrict__ Yt,
                                              float* __restrict__ prec,
                                              float* __restrict__ XLY) {
  int jt = blockIdx.x, it = blockIdx.y, s = blockIdx.z;
  bool isX = (jt < 18);
  if (isX && jt > 2 * it + 1) return;  // strictly-upper tile: skip
  int i0 = it * 128;
  int j0 = isX ? jt * 64 : (jt - 18) * 64;
  const float* Abase = P + ((size_t)s * ND + i0) * NK;
  const float* Bbase = isX ? (P + ((size_t)s * ND + j0) * NK) : (Yt + j0);

  __shared__ float Ast[32][128];
  __shared__ float Bst[32][64];
  int tid = threadIdx.x;
  int tx = tid & 15, ty = tid >> 4;
  float acc[8][4] = {};

  int arow = tid >> 1, akh = (tid & 1) * 16;
  const float* ap = Abase + (size_t)arow * NK + akh;
  const float* bp0 = isX ? (Bbase + (size_t)(arow & 63) * NK + akh) : Bbase;

  for (int k0 = 0; k0 < NK; k0 += 32) {
    __syncthreads();
    // stage A (128x32) transposed
#pragma unroll
    for (int m = 0; m < 4; ++m) {
      float4 v = *(const float4*)(ap + k0 + m * 4);
      Ast[akh + m * 4 + 0][arow] = v.x;
      Ast[akh + m * 4 + 1][arow] = v.y;
      Ast[akh + m * 4 + 2][arow] = v.z;
      Ast[akh + m * 4 + 3][arow] = v.w;
    }
    if (isX) {
      if (tid < 128) {
#pragma unroll
        for (int m = 0; m < 4; ++m) {
          float4 v = *(const float4*)(bp0 + k0 + m * 4);
          Bst[akh + m * 4 + 0][arow] = v.x;
          Bst[akh + m * 4 + 1][arow] = v.y;
          Bst[akh + m * 4 + 2][arow] = v.z;
          Bst[akh + m * 4 + 3][arow] = v.w;
        }
      }
    } else {
#pragma unroll
      for (int m = 0; m < 2; ++m) {
        int f = tid + 256 * m;
        int kk = f >> 4, j4 = (f & 15) * 4;
        float4 v = *(const float4*)(Bbase + (size_t)(k0 + kk) * NCOUT + j4);
        *(float4*)&Bst[kk][j4] = v;
      }
    }
    __syncthreads();
#pragma unroll
    for (int k = 0; k < 32; ++k) {
      float4 a0 = *(const float4*)&Ast[k][ty * 8];
      float4 a1 = *(const float4*)&Ast[k][ty * 8 + 4];
      float4 b0 = *(const float4*)&Bst[k][tx * 4];
      float ar[8] = {a0.x, a0.y, a0.z, a0.w, a1.x, a1.y, a1.z, a1.w};
      float br[4] = {b0.x, b0.y, b0.z, b0.w};
#pragma unroll
      for (int r = 0; r < 8; ++r)
#pragma unroll
        for (int e = 0; e < 4; ++e) acc[r][e] = fmaf(ar[r], br[e], acc[r][e]);
    }
  }
  if (isX) {
#pragma unroll
    for (int r = 0; r < 8; ++r) {
      int di = i0 + ty * 8 + r;
      int dj = j0 + tx * 4;
      float4 v;
      v.x = acc[r][0] + ((di == dj + 0) ? 1.f : 0.f);
      v.y = acc[r][1] + ((di == dj + 1) ? 1.f : 0.f);
      v.z = acc[r][2] + ((di == dj + 2) ? 1.f : 0.f);
      v.w = acc[r][3] + ((di == dj + 3) ? 1.f : 0.f);
      *(float4*)&prec[((size_t)s * ND + di) * ND + dj] = v;
    }
  } else {
#pragma unroll
    for (int r = 0; r < 8; ++r) {
      int di = i0 + ty * 8 + r;
      float4 v = {acc[r][0], acc[r][1], acc[r][2], acc[r][3]};
      *(float4*)&XLY[((size_t)s * ND + di) * NCOUT + j0 + tx * 4] = v;
    }
  }
}

// ---------------- blocked Cholesky, NB=64 ----------------
// one launch per panel: grid (4, 18-q), 64 threads (1 wave).
// every block register-factors the 64x64 diag (redundantly); strip 0 writes it,
// strips >0 solve their 64-row strip against it via readlane broadcasts.
__global__ __launch_bounds__(64) void k_chol_panel(float* __restrict__ L,
                                                   float* __restrict__ invd,
                                                   float* __restrict__ logd, int q) {
  const int s = blockIdx.x;
  const int strip = blockIdx.y;
  const int lane = threadIdx.x;
  const int j0 = q * 64;
  float* Ls = L + (size_t)s * D2;
  __shared__ float tile[64][65];
  for (int r = 0; r < 64; ++r) tile[r][lane] = Ls[(size_t)(j0 + r) * ND + j0 + lane];
  __syncthreads();
  float a[64];
#pragma unroll
  for (int t = 0; t < 64; ++t) a[t] = tile[lane][t];
  float diagv = 1.f;
#pragma unroll
  for (int j = 0; j < 64; ++j) {
    float dj = __shfl(a[j], j, 64);
    float rinv = 1.0f / sqrtf(dj);
    a[j] *= rinv;
    if (lane == j) diagv = a[j];
#pragma unroll
    for (int t = j + 1; t < 64; ++t) {
      float ltj = __shfl(a[j], t, 64);  // L[t][j]
      a[t] = fmaf(-a[j], ltj, a[t]);
    }
  }
  if (strip == 0) {
    __syncthreads();
#pragma unroll
    for (int t = 0; t < 64; ++t) tile[lane][t] = a[t];
    __syncthreads();
    for (int r = 0; r < 64; ++r) Ls[(size_t)(j0 + r) * ND + j0 + lane] = tile[r][lane];
    invd[s * ND + j0 + lane] = 1.0f / diagv;
    logd[s * ND + j0 + lane] = logf(diagv);
  } else {
    const int r0 = j0 + 64 * strip;
    __syncthreads();
    for (int r = 0; r < 64; ++r) tile[r][lane] = Ls[(size_t)(r0 + r) * ND + j0 + lane];
    __syncthreads();
    float b[64];
#pragma unroll
    for (int t = 0; t < 64; ++t) b[t] = tile[lane][t];
#pragma unroll
    for (int j = 0; j < 64; ++j) {
      float dj = __shfl(a[j], j, 64);  // factored diag
      b[j] *= (1.0f / dj);
#pragma unroll
      for (int t = j + 1; t < 64; ++t) {
        float ltj = __shfl(a[j], t, 64);
        b[t] = fmaf(-b[j], ltj, b[t]);
      }
    }
    __syncthreads();
#pragma unroll
    for (int t = 0; t < 64; ++t) tile[lane][t] = b[t];
    __syncthreads();
    for (int r = 0; r < 64; ++r) Ls[(size_t)(r0 + r) * ND + j0 + lane] = tile[r][lane];
  }
}

// trailing syrk: A[trailing,trailing] -= Lp_i @ Lp_j^T, 64x64 tiles, lower only
__global__ __launch_bounds__(256) void k_chol_update(float* __restrict__ L, int q) {
  int ti = blockIdx.x, tj = blockIdx.y, s = blockIdx.z;
  if (ti < tj) return;
  int j0 = q * 64;
  int r0 = j0 + 64 + ti * 64;
  int c0 = j0 + 64 + tj * 64;
  float* Ls = L + (size_t)s * D2;
  __shared__ float At[64][64];
  __shared__ float Bt[64][64];
  int tid = threadIdx.x;
  {
    int a = tid >> 2, km = (tid & 3) * 4;
#pragma unroll
    for (int m = 0; m < 4; ++m) {
      float4 v = *(const float4*)(Ls + (size_t)(r0 + a) * ND + j0 + km + m * 16);
      At[km + m * 16 + 0][a] = v.x;
      At[km + m * 16 + 1][a] = v.y;
      At[km + m * 16 + 2][a] = v.z;
      At[km + m * 16 + 3][a] = v.w;
      float4 w = *(const float4*)(Ls + (size_t)(c0 + a) * ND + j0 + km + m * 16);
      Bt[km + m * 16 + 0][a] = w.x;
      Bt[km + m * 16 + 1][a] = w.y;
      Bt[km + m * 16 + 2][a] = w.z;
      Bt[km + m * 16 + 3][a] = w.w;
    }
  }
  __syncthreads();
  int tx = tid & 15, ty = tid >> 4;
  float acc[4][4] = {};
#pragma unroll
  for (int k = 0; k < 64; ++k) {
    float4 a4 = *(const float4*)&At[k][ty * 4];
    float4 b4 = *(const float4*)&Bt[k][tx * 4];
    float ar[4] = {a4.x, a4.y, a4.z, a4.w};
    float br[4] = {b4.x, b4.y, b4.z, b4.w};
#pragma unroll
    for (int r = 0; r < 4; ++r)
#pragma unroll
      for (int e = 0; e < 4; ++e) acc[r][e] = fmaf(ar[r], br[e], acc[r][e]);
  }
#pragma unroll
  for (int r = 0; r < 4; ++r) {
    float* cp = Ls + (size_t)(r0 + ty * 4 + r) * ND + c0 + tx * 4;
    float4 c = *(const float4*)cp;
    c.x -= acc[r][0]; c.y -= acc[r][1]; c.z -= acc[r][2]; c.w -= acc[r][3];
    *(float4*)cp = c;
  }
}

// LT[i][j] = L[j][i] for j>=i (tiles)
__global__ __launch_bounds__(256) void k_transpose(const float* __restrict__ L,
                                                   float* __restrict__ LT) {
  int ti = blockIdx.x, tj = blockIdx.y, s = blockIdx.z;
  if (tj < ti) return;
  __shared__ float t[64][65];
  int i0 = ti * 64, j0 = tj * 64;
  const float* Ls = L + (size_t)s * D2;
  float* Ts = LT + (size_t)s * D2;
  int tx = threadIdx.x & 63, ty = threadIdx.x >> 6;
#pragma unroll
  for (int m = 0; m < 16; ++m) {
    int a = ty + 4 * m;
    t[a][tx] = Ls[(size_t)(j0 + a) * ND + i0 + tx];
  }
  __syncthreads();
#pragma unroll
  for (int m = 0; m < 16; ++m) {
    int a = ty + 4 * m;
    Ts[(size_t)(i0 + a) * ND + j0 + tx] = t[tx][a];
  }
}

// ---------------- fused fwd/bwd triangular solve, 1 wave per RHS column ----------------
__global__ __launch_bounds__(256) void k_solve(const float* __restrict__ L,
                                               const float* __restrict__ LT,
                                               const float* __restrict__ invd,
                                               const float* __restrict__ XLY,
                                               const float* __restrict__ Z,
                                               float* __restrict__ Wm,
                                               float* __restrict__ pp) {
  int s = blockIdx.y;
  int wave = threadIdx.x >> 6, lane = threadIdx.x & 63;
  int c = blockIdx.x * 4 + wave;
  __shared__ float xs[4][ND];
  float* x = xs[wave];
  const float* Ls = L + (size_t)s * D2;
  const float* Ts = LT + (size_t)s * D2;
  const float* iv = invd + s * ND;
  const float* bcol = XLY + (size_t)s * ND * NCOUT + c;
  const float* zrow = Z + ((size_t)s * NCOUT + c) * ND;

  // preload rhs
  for (int ii = lane; ii < ND; ii += 64) x[ii] = bcol[(size_t)ii * NCOUT];
  // forward: x = L^-1 x (in place)
  for (int i = 0; i < ND; ++i) {
    const float* Lr = Ls + (size_t)i * ND;
    int kf = i >> 6;
    float sum = 0.f;
    int j = lane;
    for (int k = 0; k < kf; ++k) { sum = fmaf(x[j], Lr[j], sum); j += 64; }
    if (j < i) sum = fmaf(x[j], Lr[j], sum);
#pragma unroll
    for (int m = 32; m >= 1; m >>= 1) sum += __shfl_xor(sum, m, 64);
    float xi = (x[i] - sum) * iv[i];
    if (lane == 0) x[i] = xi;
  }
  // backward: x = L^-T (x + z) (in place; x[j] for j>i already overwritten = solution)
  for (int i = ND - 1; i >= 0; --i) {
    const float* Tr = Ts + (size_t)i * ND;
    int kl = (i >> 6) + 1;
    float sum = 0.f;
    int j = (i & ~63) + lane;
    if (j > i) sum = fmaf(x[j], Tr[j], sum);
    j = kl * 64 + lane;
    for (int k = kl; k < 18; ++k) { sum = fmaf(x[j], Tr[j], sum); j += 64; }
#pragma unroll
    for (int m = 32; m >= 1; m >>= 1) sum += __shfl_xor(sum, m, 64);
    float xi = (x[i] + zrow[i] - sum) * iv[i];
    if (lane == 0) x[i] = xi;
  }
  // write Wm row c, accumulate per-column partial sums
  float* out = Wm + ((size_t)s * NCOUT + c) * ND;
  float wsum = 0.f, zsum = 0.f;
  for (int ii = lane; ii < ND; ii += 64) {
    float w = x[ii], z = zrow[ii];
    out[ii] = w;
    wsum = fmaf(w, w, wsum);
    zsum = fmaf(z, z, zsum);
  }
#pragma unroll
  for (int m = 32; m >= 1; m >>= 1) {
    wsum += __shfl_xor(wsum, m, 64);
    zsum += __shfl_xor(zsum, m, 64);
  }
  if (lane == 0) {
    pp[(size_t)(s * NCOUT + c) * 2 + 0] = wsum;
    pp[(size_t)(s * NCOUT + c) * 2 + 1] = zsum;
  }
}

__global__ __launch_bounds__(256) void k_finalize(const float* __restrict__ logd,
                                                  const float* __restrict__ pp,
                                                  float* __restrict__ out) {
  int s = blockIdx.x, tid = threadIdx.x;
  float lsum = 0.f;
  for (int i = tid; i < ND; i += 256) lsum += logd[s * ND + i];
  float wsum = pp[(size_t)(s * NCOUT + tid) * 2 + 0];
  float zsum = pp[(size_t)(s * NCOUT + tid) * 2 + 1];
  __shared__ float r0[256], r1[256], r2[256];
  r0[tid] = lsum; r1[tid] = wsum; r2[tid] = zsum;
  __syncthreads();
  for (int off = 128; off; off >>= 1) {
    if (tid < off) { r0[tid] += r0[tid + off]; r1[tid] += r1[tid + off]; r2[tid] += r2[tid + off]; }
    __syncthreads();
  }
  if (tid == 0) {
    float logdet = 2.0f * r0[0];
    out[s] = 0.5f * (r2[0] - r1[0]) - 128.0f * logdet;
  }
}

// ---------------- launcher ----------------
extern "C" void kernel_launch(void* const* d_in, const int* in_sizes, int n_in,
                              void* d_out, int out_size, void* d_ws, size_t ws_size,
                              hipStream_t stream) {
  const float* X = (const float*)d_in[0];
  const float* u = (const float*)d_in[1];
  const float* lp = (const float*)d_in[2];
  const float* Z = (const float*)d_in[3];
  float* out = (float*)d_out;

  float* ws = (float*)d_ws;
  float* sp   = ws;                                   // 64
  float* invd = sp + 64;                              // 4608
  float* logd = invd + (size_t)NS * ND;               // 4608
  float* pp   = logd + (size_t)NS * ND;               // 2048
  float* prec = pp + (size_t)NS * NCOUT * 2;          // 4*1152*1152
  float* LT   = prec + (size_t)NS * D2;               // 4*1152*1152
  float* XLY  = LT + (size_t)NS * D2;                 // 4*1152*256
  float* Yt   = XLY + (size_t)NS * ND * NCOUT;        // 8192*256
  float* P    = Yt + (size_t)NK * NCOUT;              // 4*1152*8192 (151 MB)

  k_sqrtp<<<1, 64, 0, stream>>>(lp, sp);
  k_patches<<<dim3(ND, NS), 256, 0, stream>>>(X, sp, P);
  k_yt<<<dim3(8, 8, NB), 256, 0, stream>>>(u, sp, Yt);
  k_gemm<<<dim3(22, 9, NS), 256, 0, stream>>>(P, Yt, prec, XLY);

  for (int q = 0; q < 18; ++q) {
    k_chol_panel<<<dim3(NS, 18 - q), 64, 0, stream>>>(prec, invd, logd, q);
    if (q < 17) {
      int m = 17 - q;
      k_chol_update<<<dim3(m, m, NS), 256, 0, stream>>>(prec, q);
    }
  }
  k_transpose<<<dim3(18, 18, NS), 256, 0, stream>>>(prec, LT);
  k_solve<<<dim3(64, NS), 256, 0, stream>>>(prec, LT, invd, XLY, Z, out, pp);
  k_finalize<<<NS, 256, 0, stream>>>(logd, pp, out + (size_t)NS * NCOUT * ND);
}

// Round 2
// 3229.601 us; speedup vs baseline: 2.3546x; 2.3546x over previous
//
#include <hip/hip_runtime.h>
#include <math.h>

#define NS 4
#define NB 32
#define CIN 128
#define NCOUT 256
#define HWN 256
#define ND 1152
#define NK 8192   // NB*HWN
static const size_t D2 = (size_t)ND * ND;

// ---------------- small prep kernels ----------------

__global__ void k_sqrtp(const float* __restrict__ lp, float* __restrict__ sp,
                        float* __restrict__ pp) {
  int b = threadIdx.x;
  if (b < NB) sp[b] = expf(0.5f * lp[b]);
  if (b < 8) pp[b] = 0.f;
}

// P[s][d][b*256+p] = sqrtp[b] * X[s][b][c][y+ky-1][x+kx-1] (zero padded), d=(c*3+ky)*3+kx
__global__ __launch_bounds__(256) void k_patches(const float* __restrict__ X,
                                                 const float* __restrict__ sp,
                                                 float* __restrict__ P) {
  int d = blockIdx.x, s = blockIdx.y, p = threadIdx.x;
  int c = d / 9, r = d % 9, ky = r / 3, kx = r % 3;
  int yy = (p >> 4) + ky - 1, xx = (p & 15) + kx - 1;
  bool ok = (yy >= 0 && yy < 16 && xx >= 0 && xx < 16);
  int xoff = yy * 16 + xx;
  float* Pd = P + ((size_t)s * ND + d) * NK + p;
  for (int b = 0; b < NB; ++b) {
    float v = 0.f;
    if (ok) v = X[((size_t)(s * NB + b) * CIN + c) * HWN + xoff] * sp[b];
    Pd[b * HWN] = v;
  }
}

// Yt[b*256+p][c] = sqrtp[b]*u[b][c][p]   (transpose via LDS)
__global__ __launch_bounds__(256) void k_yt(const float* __restrict__ u,
                                            const float* __restrict__ sp,
                                            float* __restrict__ Yt) {
  __shared__ float t[32][33];
  int c0 = blockIdx.x * 32, p0 = blockIdx.y * 32, b = blockIdx.z;
  int tx = threadIdx.x & 31, ty = threadIdx.x >> 5;  // 32 x 8
  float s = sp[b];
#pragma unroll
  for (int k = 0; k < 4; ++k) {
    int c = c0 + ty + 8 * k;
    t[ty + 8 * k][tx] = u[((size_t)b * NCOUT + c) * HWN + p0 + tx] * s;
  }
  __syncthreads();
#pragma unroll
  for (int k = 0; k < 4; ++k) {
    int p = p0 + ty + 8 * k;
    Yt[((size_t)b * HWN + p) * NCOUT + c0 + tx] = t[tx][ty + 8 * k];
  }
}

// ---------------- fused XLX (syrk, lower) + XLY GEMM ----------------
__global__ __launch_bounds__(256) void k_gemm(const float* __restrict__ P,
                                              const float* __restrict__ Yt,
                                              float* __restrict__ prec,
                                              float* __restrict__ XLY) {
  int jt = blockIdx.x, it = blockIdx.y, s = blockIdx.z;
  bool isX = (jt < 18);
  if (isX && jt > 2 * it + 1) return;  // strictly-upper tile: skip
  int i0 = it * 128;
  int j0 = isX ? jt * 64 : (jt - 18) * 64;
  const float* Abase = P + ((size_t)s * ND + i0) * NK;
  const float* Bbase = isX ? (P + ((size_t)s * ND + j0) * NK) : (Yt + j0);

  __shared__ float Ast[32][128];
  __shared__ float Bst[32][64];
  int tid = threadIdx.x;
  int tx = tid & 15, ty = tid >> 4;
  float acc[8][4] = {};

  int arow = tid >> 1, akh = (tid & 1) * 16;
  const float* ap = Abase + (size_t)arow * NK + akh;
  const float* bp0 = isX ? (Bbase + (size_t)(arow & 63) * NK + akh) : Bbase;

  for (int k0 = 0; k0 < NK; k0 += 32) {
    __syncthreads();
#pragma unroll
    for (int m = 0; m < 4; ++m) {
      float4 v = *(const float4*)(ap + k0 + m * 4);
      Ast[akh + m * 4 + 0][arow] = v.x;
      Ast[akh + m * 4 + 1][arow] = v.y;
      Ast[akh + m * 4 + 2][arow] = v.z;
      Ast[akh + m * 4 + 3][arow] = v.w;
    }
    if (isX) {
      if (tid < 128) {
#pragma unroll
        for (int m = 0; m < 4; ++m) {
          float4 v = *(const float4*)(bp0 + k0 + m * 4);
          Bst[akh + m * 4 + 0][arow] = v.x;
          Bst[akh + m * 4 + 1][arow] = v.y;
          Bst[akh + m * 4 + 2][arow] = v.z;
          Bst[akh + m * 4 + 3][arow] = v.w;
        }
      }
    } else {
#pragma unroll
      for (int m = 0; m < 2; ++m) {
        int f = tid + 256 * m;
        int kk = f >> 4, j4 = (f & 15) * 4;
        float4 v = *(const float4*)(Bbase + (size_t)(k0 + kk) * NCOUT + j4);
        *(float4*)&Bst[kk][j4] = v;
      }
    }
    __syncthreads();
#pragma unroll
    for (int k = 0; k < 32; ++k) {
      float4 a0 = *(const float4*)&Ast[k][ty * 8];
      float4 a1 = *(const float4*)&Ast[k][ty * 8 + 4];
      float4 b0 = *(const float4*)&Bst[k][tx * 4];
      float ar[8] = {a0.x, a0.y, a0.z, a0.w, a1.x, a1.y, a1.z, a1.w};
      float br[4] = {b0.x, b0.y, b0.z, b0.w};
#pragma unroll
      for (int r = 0; r < 8; ++r)
#pragma unroll
        for (int e = 0; e < 4; ++e) acc[r][e] = fmaf(ar[r], br[e], acc[r][e]);
    }
  }
  if (isX) {
#pragma unroll
    for (int r = 0; r < 8; ++r) {
      int di = i0 + ty * 8 + r;
      int dj = j0 + tx * 4;
      float4 v;
      v.x = acc[r][0] + ((di == dj + 0) ? 1.f : 0.f);
      v.y = acc[r][1] + ((di == dj + 1) ? 1.f : 0.f);
      v.z = acc[r][2] + ((di == dj + 2) ? 1.f : 0.f);
      v.w = acc[r][3] + ((di == dj + 3) ? 1.f : 0.f);
      *(float4*)&prec[((size_t)s * ND + di) * ND + dj] = v;
    }
  } else {
#pragma unroll
    for (int r = 0; r < 8; ++r) {
      int di = i0 + ty * 8 + r;
      float4 v = {acc[r][0], acc[r][1], acc[r][2], acc[r][3]};
      *(float4*)&XLY[((size_t)s * ND + di) * NCOUT + j0 + tx * 4] = v;
    }
  }
}

// ---------------- blocked Cholesky, NB=64 ----------------
__global__ __launch_bounds__(64) void k_chol_panel(float* __restrict__ L,
                                                   float* __restrict__ invd,
                                                   float* __restrict__ logd, int q) {
  const int s = blockIdx.x;
  const int strip = blockIdx.y;
  const int lane = threadIdx.x;
  const int j0 = q * 64;
  float* Ls = L + (size_t)s * D2;
  __shared__ float tile[64][65];
  for (int r = 0; r < 64; ++r) tile[r][lane] = Ls[(size_t)(j0 + r) * ND + j0 + lane];
  __syncthreads();
  float a[64];
#pragma unroll
  for (int t = 0; t < 64; ++t) a[t] = tile[lane][t];
  float diagv = 1.f;
#pragma unroll
  for (int j = 0; j < 64; ++j) {
    float dj = __shfl(a[j], j, 64);
    float rinv = 1.0f / sqrtf(dj);
    a[j] *= rinv;
    if (lane == j) diagv = a[j];
#pragma unroll
    for (int t = j + 1; t < 64; ++t) {
      float ltj = __shfl(a[j], t, 64);
      a[t] = fmaf(-a[j], ltj, a[t]);
    }
  }
  if (strip == 0) {
    __syncthreads();
#pragma unroll
    for (int t = 0; t < 64; ++t) tile[lane][t] = a[t];
    __syncthreads();
    for (int r = 0; r < 64; ++r) Ls[(size_t)(j0 + r) * ND + j0 + lane] = tile[r][lane];
    invd[s * ND + j0 + lane] = 1.0f / diagv;
    logd[s * ND + j0 + lane] = logf(diagv);
  } else {
    const int r0 = j0 + 64 * strip;
    __syncthreads();
    for (int r = 0; r < 64; ++r) tile[r][lane] = Ls[(size_t)(r0 + r) * ND + j0 + lane];
    __syncthreads();
    float b[64];
#pragma unroll
    for (int t = 0; t < 64; ++t) b[t] = tile[lane][t];
#pragma unroll
    for (int j = 0; j < 64; ++j) {
      float dj = __shfl(a[j], j, 64);
      b[j] *= (1.0f / dj);
#pragma unroll
      for (int t = j + 1; t < 64; ++t) {
        float ltj = __shfl(a[j], t, 64);
        b[t] = fmaf(-b[j], ltj, b[t]);
      }
    }
    __syncthreads();
#pragma unroll
    for (int t = 0; t < 64; ++t) tile[lane][t] = b[t];
    __syncthreads();
    for (int r = 0; r < 64; ++r) Ls[(size_t)(r0 + r) * ND + j0 + lane] = tile[r][lane];
  }
}

__global__ __launch_bounds__(256) void k_chol_update(float* __restrict__ L, int q) {
  int ti = blockIdx.x, tj = blockIdx.y, s = blockIdx.z;
  if (ti < tj) return;
  int j0 = q * 64;
  int r0 = j0 + 64 + ti * 64;
  int c0 = j0 + 64 + tj * 64;
  float* Ls = L + (size_t)s * D2;
  __shared__ float At[64][64];
  __shared__ float Bt[64][64];
  int tid = threadIdx.x;
  {
    int a = tid >> 2, km = (tid & 3) * 4;
#pragma unroll
    for (int m = 0; m < 4; ++m) {
      float4 v = *(const float4*)(Ls + (size_t)(r0 + a) * ND + j0 + km + m * 16);
      At[km + m * 16 + 0][a] = v.x;
      At[km + m * 16 + 1][a] = v.y;
      At[km + m * 16 + 2][a] = v.z;
      At[km + m * 16 + 3][a] = v.w;
      float4 w = *(const float4*)(Ls + (size_t)(c0 + a) * ND + j0 + km + m * 16);
      Bt[km + m * 16 + 0][a] = w.x;
      Bt[km + m * 16 + 1][a] = w.y;
      Bt[km + m * 16 + 2][a] = w.z;
      Bt[km + m * 16 + 3][a] = w.w;
    }
  }
  __syncthreads();
  int tx = tid & 15, ty = tid >> 4;
  float acc[4][4] = {};
#pragma unroll
  for (int k = 0; k < 64; ++k) {
    float4 a4 = *(const float4*)&At[k][ty * 4];
    float4 b4 = *(const float4*)&Bt[k][tx * 4];
    float ar[4] = {a4.x, a4.y, a4.z, a4.w};
    float br[4] = {b4.x, b4.y, b4.z, b4.w};
#pragma unroll
    for (int r = 0; r < 4; ++r)
#pragma unroll
      for (int e = 0; e < 4; ++e) acc[r][e] = fmaf(ar[r], br[e], acc[r][e]);
  }
#pragma unroll
  for (int r = 0; r < 4; ++r) {
    float* cp = Ls + (size_t)(r0 + ty * 4 + r) * ND + c0 + tx * 4;
    float4 c = *(const float4*)cp;
    c.x -= acc[r][0]; c.y -= acc[r][1]; c.z -= acc[r][2]; c.w -= acc[r][3];
    *(float4*)cp = c;
  }
}

// LT[i][j] = L[j][i] for j>=i (tiles)
__global__ __launch_bounds__(256) void k_transpose(const float* __restrict__ L,
                                                   float* __restrict__ LT) {
  int ti = blockIdx.x, tj = blockIdx.y, s = blockIdx.z;
  if (tj < ti) return;
  __shared__ float t[64][65];
  int i0 = ti * 64, j0 = tj * 64;
  const float* Ls = L + (size_t)s * D2;
  float* Ts = LT + (size_t)s * D2;
  int tx = threadIdx.x & 63, ty = threadIdx.x >> 6;
#pragma unroll
  for (int m = 0; m < 16; ++m) {
    int a = ty + 4 * m;
    t[a][tx] = Ls[(size_t)(j0 + a) * ND + i0 + tx];
  }
  __syncthreads();
#pragma unroll
  for (int m = 0; m < 16; ++m) {
    int a = ty + 4 * m;
    Ts[(size_t)(i0 + a) * ND + j0 + tx] = t[tx][a];
  }
}

// ---------------- invert the 18 diagonal 64x64 blocks (lower-tri) ----------------
// lane = column j; forward substitution, x kept in a per-lane LDS column.
__global__ __launch_bounds__(64) void k_invdiag(const float* __restrict__ L,
                                                float* __restrict__ InvD,
                                                float* __restrict__ InvDT) {
  int q = blockIdx.x, s = blockIdx.y;
  int lane = threadIdx.x;
  const float* Ls = L + (size_t)s * D2;
  __shared__ float Ds[64][65];
  __shared__ float Xls[64][64];
  for (int r = 0; r < 64; ++r)
    Ds[r][lane] = Ls[(size_t)(q * 64 + r) * ND + q * 64 + lane];
  __syncthreads();
  for (int t = 0; t < 64; ++t) {
    float sum = (t == lane) ? 1.f : 0.f;
    for (int k = 0; k < t; ++k) sum = fmaf(-Ds[t][k], Xls[k][lane], sum);
    Xls[t][lane] = sum / Ds[t][t];
  }
  __syncthreads();
  float* od = InvD + (size_t)(s * 18 + q) * 4096;
  float* ot = InvDT + (size_t)(s * 18 + q) * 4096;
  for (int t = 0; t < 64; ++t) {
    od[t * 64 + lane] = Xls[t][lane];   // InvD[t][j]
    ot[t * 64 + lane] = Xls[lane][t];   // InvDT[t][j] = InvD[j][t]
  }
}

// ---------------- one stage of the blocked triangular solve ----------------
// FWD: r = q + bx; solve X[q] = InvD[q] @ B[q]; r==q writes X, r>q does B[r] -= L[r,q] @ X[q].
// BWD: r = bx (0..q); uses LT and InvDT; r<q updates B, r==q writes X.
// Every block recomputes the 64x64 diag-solve for its own 64-column slice (no race:
// B[q] is never written in stage q; the solved block goes to the separate X buffer).
template <bool FWD>
__global__ __launch_bounds__(256) void k_stage(const float* __restrict__ M,
                                               const float* __restrict__ Dinv,
                                               float* __restrict__ B,
                                               float* __restrict__ X, int q) {
  int s = blockIdx.z, ct = blockIdx.y;
  int r = FWD ? (q + blockIdx.x) : (int)blockIdx.x;
  int c0 = ct * 64;
  const float* Ms = M + (size_t)s * D2;
  const float* Dq = Dinv + (size_t)(s * 18 + q) * 4096;
  float* Bs = B + (size_t)s * ND * NCOUT;
  float* Xs = X + (size_t)s * ND * NCOUT;

  __shared__ float As[64][68];  // [k][i] (transposed A operand)
  __shared__ float Bt[64][64];  // [k][c]
  int tid = threadIdx.x;
  int row = tid >> 2, kq = (tid & 3) * 16;

  // stage Dinv transposed: As[k][i] = Dq[i][k]
#pragma unroll
  for (int m = 0; m < 4; ++m) {
    float4 v = *(const float4*)(Dq + row * 64 + kq + m * 4);
    As[kq + m * 4 + 0][row] = v.x;
    As[kq + m * 4 + 1][row] = v.y;
    As[kq + m * 4 + 2][row] = v.z;
    As[kq + m * 4 + 3][row] = v.w;
  }
  // stage B[q] tile: Bt[k][c]
#pragma unroll
  for (int m = 0; m < 4; ++m)
    *(float4*)&Bt[row][kq + m * 4] =
        *(const float4*)(Bs + (size_t)(q * 64 + row) * NCOUT + c0 + kq + m * 4);
  __syncthreads();

  int tx = tid & 15, ty = tid >> 4;
  float acc[4][4] = {};
#pragma unroll
  for (int k = 0; k < 64; ++k) {
    float4 a4 = *(const float4*)&As[k][ty * 4];
    float4 b4 = *(const float4*)&Bt[k][tx * 4];
    float ar[4] = {a4.x, a4.y, a4.z, a4.w};
    float br[4] = {b4.x, b4.y, b4.z, b4.w};
#pragma unroll
    for (int rr = 0; rr < 4; ++rr)
#pragma unroll
      for (int e = 0; e < 4; ++e) acc[rr][e] = fmaf(ar[rr], br[e], acc[rr][e]);
  }

  if (r == q) {  // diag block: write solved X[q] tile
#pragma unroll
    for (int rr = 0; rr < 4; ++rr) {
      float4 v = {acc[rr][0], acc[rr][1], acc[rr][2], acc[rr][3]};
      *(float4*)(Xs + (size_t)(q * 64 + ty * 4 + rr) * NCOUT + c0 + tx * 4) = v;
    }
    return;
  }

  __syncthreads();
  // Xq (GEMM1 out) -> Bt[k][c]; restage As = M block (r,q) transposed
#pragma unroll
  for (int rr = 0; rr < 4; ++rr) {
    float4 v = {acc[rr][0], acc[rr][1], acc[rr][2], acc[rr][3]};
    *(float4*)&Bt[ty * 4 + rr][tx * 4] = v;
  }
#pragma unroll
  for (int m = 0; m < 4; ++m) {
    float4 v = *(const float4*)(Ms + (size_t)(r * 64 + row) * ND + q * 64 + kq + m * 4);
    As[kq + m * 4 + 0][row] = v.x;
    As[kq + m * 4 + 1][row] = v.y;
    As[kq + m * 4 + 2][row] = v.z;
    As[kq + m * 4 + 3][row] = v.w;
  }
  __syncthreads();

  float acc2[4][4] = {};
#pragma unroll
  for (int k = 0; k < 64; ++k) {
    float4 a4 = *(const float4*)&As[k][ty * 4];
    float4 b4 = *(const float4*)&Bt[k][tx * 4];
    float ar[4] = {a4.x, a4.y, a4.z, a4.w};
    float br[4] = {b4.x, b4.y, b4.z, b4.w};
#pragma unroll
    for (int rr = 0; rr < 4; ++rr)
#pragma unroll
      for (int e = 0; e < 4; ++e) acc2[rr][e] = fmaf(ar[rr], br[e], acc2[rr][e]);
  }
#pragma unroll
  for (int rr = 0; rr < 4; ++rr) {
    float4* p = (float4*)(Bs + (size_t)(r * 64 + ty * 4 + rr) * NCOUT + c0 + tx * 4);
    float4 c = *p;
    c.x -= acc2[rr][0]; c.y -= acc2[rr][1]; c.z -= acc2[rr][2]; c.w -= acc2[rr][3];
    *p = c;
  }
}

// T[d][c] += Z[s][c][d]  (in-place on Xf) + per-sample sum(Z^2) via atomics
__global__ __launch_bounds__(256) void k_addz(float* __restrict__ Xf,
                                              const float* __restrict__ Z,
                                              float* __restrict__ pp) {
  int dt = blockIdx.x, ct = blockIdx.y, s = blockIdx.z;
  int d0 = dt * 64, c0 = ct * 64;
  __shared__ float Zt[64][68];
  int tid = threadIdx.x;
  int row = tid >> 2, kq = (tid & 3) * 16;
  float zp = 0.f;
#pragma unroll
  for (int m = 0; m < 4; ++m) {
    float4 v = *(const float4*)(Z + ((size_t)(s * NCOUT) + c0 + row) * ND + d0 + kq + m * 4);
    Zt[kq + m * 4 + 0][row] = v.x;
    Zt[kq + m * 4 + 1][row] = v.y;
    Zt[kq + m * 4 + 2][row] = v.z;
    Zt[kq + m * 4 + 3][row] = v.w;
    zp += v.x * v.x + v.y * v.y + v.z * v.z + v.w * v.w;
  }
  __syncthreads();
#pragma unroll
  for (int m = 0; m < 4; ++m) {
    float4* p = (float4*)(Xf + (size_t)(s * ND + d0 + row) * NCOUT + c0 + kq + m * 4);
    float4 x = *p;
    x.x += Zt[row][kq + m * 4 + 0];
    x.y += Zt[row][kq + m * 4 + 1];
    x.z += Zt[row][kq + m * 4 + 2];
    x.w += Zt[row][kq + m * 4 + 3];
    *p = x;
  }
#pragma unroll
  for (int m2 = 32; m2 >= 1; m2 >>= 1) zp += __shfl_xor(zp, m2, 64);
  if ((tid & 63) == 0) atomicAdd(pp + s, zp);
}

// Wm[s][c][d] = Xb[s][d][c]  + per-sample sum(Wm^2) via atomics
__global__ __launch_bounds__(256) void k_writewm(const float* __restrict__ Xb,
                                                 float* __restrict__ Wm,
                                                 float* __restrict__ pp) {
  int dt = blockIdx.x, ct = blockIdx.y, s = blockIdx.z;
  int d0 = dt * 64, c0 = ct * 64;
  __shared__ float T[64][68];
  int tid = threadIdx.x;
  int row = tid >> 2, kq = (tid & 3) * 16;
  float wp = 0.f;
#pragma unroll
  for (int m = 0; m < 4; ++m) {
    float4 v = *(const float4*)(Xb + (size_t)(s * ND + d0 + row) * NCOUT + c0 + kq + m * 4);
    *(float4*)&T[row][kq + m * 4] = v;
    wp += v.x * v.x + v.y * v.y + v.z * v.z + v.w * v.w;
  }
  __syncthreads();
#pragma unroll
  for (int m = 0; m < 4; ++m) {
    float4 w;
    w.x = T[kq + m * 4 + 0][row];
    w.y = T[kq + m * 4 + 1][row];
    w.z = T[kq + m * 4 + 2][row];
    w.w = T[kq + m * 4 + 3][row];
    *(float4*)(Wm + ((size_t)(s * NCOUT) + c0 + row) * ND + d0 + kq + m * 4) = w;
  }
#pragma unroll
  for (int m2 = 32; m2 >= 1; m2 >>= 1) wp += __shfl_xor(wp, m2, 64);
  if ((tid & 63) == 0) atomicAdd(pp + 4 + s, wp);
}

__global__ __launch_bounds__(256) void k_finalize(const float* __restrict__ logd,
                                                  const float* __restrict__ pp,
                                                  float* __restrict__ out) {
  int s = blockIdx.x, tid = threadIdx.x;
  __shared__ float r0[256];
  float l = 0.f;
  for (int i = tid; i < ND; i += 256) l += logd[s * ND + i];
  r0[tid] = l;
  __syncthreads();
  for (int off = 128; off; off >>= 1) {
    if (tid < off) r0[tid] += r0[tid + off];
    __syncthreads();
  }
  if (tid == 0) {
    float logdet = 2.0f * r0[0];
    out[s] = 0.5f * (pp[s] - pp[4 + s]) - 128.0f * logdet;
  }
}

// ---------------- launcher ----------------
extern "C" void kernel_launch(void* const* d_in, const int* in_sizes, int n_in,
                              void* d_out, int out_size, void* d_ws, size_t ws_size,
                              hipStream_t stream) {
  const float* X = (const float*)d_in[0];
  const float* u = (const float*)d_in[1];
  const float* lp = (const float*)d_in[2];
  const float* Z = (const float*)d_in[3];
  float* out = (float*)d_out;

  float* ws = (float*)d_ws;
  float* sp    = ws;                                   // 64
  float* invd  = sp + 64;                              // 4608
  float* logd  = invd + (size_t)NS * ND;               // 4608
  float* pp    = logd + (size_t)NS * ND;               // 64 (8 used)
  float* InvD  = pp + 64;                              // 4*18*4096
  float* InvDT = InvD + (size_t)NS * 18 * 4096;        // 4*18*4096
  float* Xf    = InvDT + (size_t)NS * 18 * 4096;       // 4*1152*256
  float* prec  = Xf + (size_t)NS * ND * NCOUT;         // 4*1152*1152
  float* LT    = prec + (size_t)NS * D2;               // 4*1152*1152
  float* XLY   = LT + (size_t)NS * D2;                 // 4*1152*256 (also reused as Xb)
  float* Yt    = XLY + (size_t)NS * ND * NCOUT;        // 8192*256
  float* P     = Yt + (size_t)NK * NCOUT;              // 4*1152*8192
  float* Xb    = XLY;  // safe alias: BWD never reads Xb, FWD is done with XLY

  k_sqrtp<<<1, 64, 0, stream>>>(lp, sp, pp);
  k_patches<<<dim3(ND, NS), 256, 0, stream>>>(X, sp, P);
  k_yt<<<dim3(8, 8, NB), 256, 0, stream>>>(u, sp, Yt);
  k_gemm<<<dim3(22, 9, NS), 256, 0, stream>>>(P, Yt, prec, XLY);

  for (int q = 0; q < 18; ++q) {
    k_chol_panel<<<dim3(NS, 18 - q), 64, 0, stream>>>(prec, invd, logd, q);
    if (q < 17) {
      int m = 17 - q;
      k_chol_update<<<dim3(m, m, NS), 256, 0, stream>>>(prec, q);
    }
  }
  k_transpose<<<dim3(18, 18, NS), 256, 0, stream>>>(prec, LT);
  k_invdiag<<<dim3(18, NS), 64, 0, stream>>>(prec, InvD, InvDT);

  // forward solve: Xf = L^-1 XLY (B updated in place, solved blocks -> Xf)
  for (int q = 0; q < 18; ++q)
    k_stage<true><<<dim3(18 - q, 4, NS), 256, 0, stream>>>(prec, InvD, XLY, Xf, q);
  // T = Xf + Z^T (in place) + sum(Z^2)
  k_addz<<<dim3(18, 4, NS), 256, 0, stream>>>(Xf, Z, pp);
  // backward solve: Xb = L^-T T
  for (int q = 17; q >= 0; --q)
    k_stage<false><<<dim3(q + 1, 4, NS), 256, 0, stream>>>(LT, InvDT, Xf, Xb, q);

  k_writewm<<<dim3(18, 4, NS), 256, 0, stream>>>(Xb, out, pp);
  k_finalize<<<NS, 256, 0, stream>>>(logd, pp, out + (size_t)NS * NCOUT * ND);
}

// Round 3
// 2147.585 us; speedup vs baseline: 3.5409x; 1.5038x over previous
//
#include <hip/hip_runtime.h>
#include <math.h>

#define NS 4
#define NB 32
#define CIN 128
#define NCOUT 256
#define HWN 256
#define ND 1152
#define NK 8192   // NB*HWN
static const size_t D2 = (size_t)ND * ND;

typedef __attribute__((ext_vector_type(8))) short bf16x8;
typedef __attribute__((ext_vector_type(4))) float f32x4;

static __device__ inline unsigned short f2bf(float x) {
  unsigned int u = __float_as_uint(x);
  unsigned int r = (u + 0x7fffu + ((u >> 16) & 1u)) >> 16;
  return (unsigned short)r;
}
static __device__ inline float bf2f(unsigned short h) {
  return __uint_as_float(((unsigned int)h) << 16);
}

// ---------------- small prep kernels ----------------

__global__ void k_sqrtp(const float* __restrict__ lp, float* __restrict__ sp,
                        float* __restrict__ pp) {
  int b = threadIdx.x;
  if (b < NB) sp[b] = expf(0.5f * lp[b]);
  if (b < 8) pp[b] = 0.f;
}

// P[s][d][b*256+p] = sqrtp[b]*X[s][b][c][y+ky-1][x+kx-1], split into bf16 hi/lo
__global__ __launch_bounds__(256) void k_patches(const float* __restrict__ X,
                                                 const float* __restrict__ sp,
                                                 unsigned short* __restrict__ Phi,
                                                 unsigned short* __restrict__ Plo) {
  int d = blockIdx.x, s = blockIdx.y, p = threadIdx.x;
  int c = d / 9, r = d % 9, ky = r / 3, kx = r % 3;
  int yy = (p >> 4) + ky - 1, xx = (p & 15) + kx - 1;
  bool ok = (yy >= 0 && yy < 16 && xx >= 0 && xx < 16);
  int xoff = yy * 16 + xx;
  size_t base = ((size_t)s * ND + d) * NK + p;
  for (int b = 0; b < NB; ++b) {
    float v = 0.f;
    if (ok) v = X[((size_t)(s * NB + b) * CIN + c) * HWN + xoff] * sp[b];
    unsigned short h = f2bf(v);
    Phi[base + b * HWN] = h;
    Plo[base + b * HWN] = f2bf(v - bf2f(h));
  }
}

// Ytt[c][b*256+p] = sqrtp[b]*u[b][c][p], split hi/lo (sample-independent)
__global__ __launch_bounds__(256) void k_ytt(const float* __restrict__ u,
                                             const float* __restrict__ sp,
                                             unsigned short* __restrict__ Yhi,
                                             unsigned short* __restrict__ Ylo) {
  int c = blockIdx.x, p = threadIdx.x;
  for (int b = 0; b < NB; ++b) {
    float v = sp[b] * u[((size_t)b * NCOUT + c) * HWN + p];
    unsigned short h = f2bf(v);
    size_t idx = (size_t)c * NK + b * HWN + p;
    Yhi[idx] = h;
    Ylo[idx] = f2bf(v - bf2f(h));
  }
}

// ---------------- bf16x3 MFMA fused XLX (lower 128-tiles) + XLY ----------------
// grid (11, 9, 4): jt<=it -> XLX 128x128 tile; jt in {9,10} -> XLY col-half; else idle.
__global__ __launch_bounds__(256) void k_gemm_mfma(
    const unsigned short* __restrict__ Phi, const unsigned short* __restrict__ Plo,
    const unsigned short* __restrict__ Yhi, const unsigned short* __restrict__ Ylo,
    float* __restrict__ prec, float* __restrict__ XLY) {
  int jt = blockIdx.x, it = blockIdx.y, s = blockIdx.z;
  bool isX = (jt <= it);
  if (!isX && jt < 9) return;
  int i0 = it * 128;
  int j0;
  const unsigned short *Bh, *Bl;
  if (isX) {
    j0 = jt * 128;
    Bh = Phi + ((size_t)s * ND + j0) * NK;
    Bl = Plo + ((size_t)s * ND + j0) * NK;
  } else {
    j0 = (jt - 9) * 128;
    Bh = Yhi + (size_t)j0 * NK;
    Bl = Ylo + (size_t)j0 * NK;
  }
  const unsigned short* Ah = Phi + ((size_t)s * ND + i0) * NK;
  const unsigned short* Al = Plo + ((size_t)s * ND + i0) * NK;

  __shared__ unsigned short sAh[4096], sAl[4096], sBh[4096], sBl[4096];
  int tid = threadIdx.x, wave = tid >> 6, lane = tid & 63;
  int wr = wave >> 1, wc = wave & 1;

  f32x4 zero = {0.f, 0.f, 0.f, 0.f};
  f32x4 acc[4][4];
#pragma unroll
  for (int m = 0; m < 4; ++m)
#pragma unroll
    for (int n = 0; n < 4; ++n) acc[m][n] = zero;

  const unsigned short* srcs[4] = {Ah, Al, Bh, Bl};
  unsigned short* dsts[4] = {sAh, sAl, sBh, sBl};
  int r0l = lane >> 2;          // row within 16-row chunk
  int ke = (lane & 3) * 8;      // k element offset
  int arow0 = wr * 64 + (lane & 15);
  int brow0 = wc * 64 + (lane & 15);
  int koff = (lane >> 4) * 8;

  for (int k0 = 0; k0 < NK; k0 += 32) {
    __syncthreads();
#pragma unroll
    for (int f = 0; f < 4; ++f) {
#pragma unroll
      for (int cc = 0; cc < 2; ++cc) {
        int c = wave * 2 + cc;
        const unsigned short* g = srcs[f] + (size_t)(c * 16 + r0l) * NK + k0 + ke;
        unsigned short* l = dsts[f] + c * 512;  // wave-uniform base; HW adds lane*16B
        __builtin_amdgcn_global_load_lds(
            (const __attribute__((address_space(1))) void*)g,
            (__attribute__((address_space(3))) void*)l, 16, 0, 0);
      }
    }
    __syncthreads();
    bf16x8 ah[4], al[4], bh[4], bl[4];
#pragma unroll
    for (int m = 0; m < 4; ++m) {
      int off = (arow0 + m * 16) * 32 + koff;
      ah[m] = *(const bf16x8*)&sAh[off];
      al[m] = *(const bf16x8*)&sAl[off];
    }
#pragma unroll
    for (int n = 0; n < 4; ++n) {
      int off = (brow0 + n * 16) * 32 + koff;
      bh[n] = *(const bf16x8*)&sBh[off];
      bl[n] = *(const bf16x8*)&sBl[off];
    }
#pragma unroll
    for (int m = 0; m < 4; ++m)
#pragma unroll
      for (int n = 0; n < 4; ++n) {
        acc[m][n] = __builtin_amdgcn_mfma_f32_16x16x32_bf16(ah[m], bh[n], acc[m][n], 0, 0, 0);
        acc[m][n] = __builtin_amdgcn_mfma_f32_16x16x32_bf16(ah[m], bl[n], acc[m][n], 0, 0, 0);
        acc[m][n] = __builtin_amdgcn_mfma_f32_16x16x32_bf16(al[m], bh[n], acc[m][n], 0, 0, 0);
      }
  }

  if (isX) {
    float* base = prec + (size_t)s * D2;
#pragma unroll
    for (int m = 0; m < 4; ++m) {
      int row = i0 + wr * 64 + m * 16 + (lane >> 4) * 4;
#pragma unroll
      for (int n = 0; n < 4; ++n) {
        int col = j0 + wc * 64 + n * 16 + (lane & 15);
        float* cp = base + (size_t)row * ND + col;
#pragma unroll
        for (int r = 0; r < 4; ++r) {
          float v = acc[m][n][r];
          if (row + r == col) v += 1.f;
          cp[(size_t)r * ND] = v;
        }
      }
    }
  } else {
    float* base = XLY + (size_t)s * ND * NCOUT;
#pragma unroll
    for (int m = 0; m < 4; ++m) {
      int row = i0 + wr * 64 + m * 16 + (lane >> 4) * 4;
#pragma unroll
      for (int n = 0; n < 4; ++n) {
        int col = j0 + wc * 64 + n * 16 + (lane & 15);
        float* cp = base + (size_t)row * NCOUT + col;
#pragma unroll
        for (int r = 0; r < 4; ++r) cp[(size_t)r * NCOUT] = acc[m][n][r];
      }
    }
  }
}

// ---------------- blocked Cholesky, NB=64 ----------------
__global__ __launch_bounds__(64) void k_chol_panel(float* __restrict__ L,
                                                   float* __restrict__ invd,
                                                   float* __restrict__ logd, int q) {
  const int s = blockIdx.x;
  const int strip = blockIdx.y;
  const int lane = threadIdx.x;
  const int j0 = q * 64;
  float* Ls = L + (size_t)s * D2;
  __shared__ float tile[64][65];
  for (int r = 0; r < 64; ++r) tile[r][lane] = Ls[(size_t)(j0 + r) * ND + j0 + lane];
  __syncthreads();
  float a[64];
#pragma unroll
  for (int t = 0; t < 64; ++t) a[t] = tile[lane][t];
  float diagv = 1.f;
#pragma unroll
  for (int j = 0; j < 64; ++j) {
    float dj = __shfl(a[j], j, 64);
    float rinv = 1.0f / sqrtf(dj);
    a[j] *= rinv;
    if (lane == j) diagv = a[j];
#pragma unroll
    for (int t = j + 1; t < 64; ++t) {
      float ltj = __shfl(a[j], t, 64);
      a[t] = fmaf(-a[j], ltj, a[t]);
    }
  }
  if (strip == 0) {
    __syncthreads();
#pragma unroll
    for (int t = 0; t < 64; ++t) tile[lane][t] = a[t];
    __syncthreads();
    for (int r = 0; r < 64; ++r) Ls[(size_t)(j0 + r) * ND + j0 + lane] = tile[r][lane];
    invd[s * ND + j0 + lane] = 1.0f / diagv;
    logd[s * ND + j0 + lane] = logf(diagv);
  } else {
    const int r0 = j0 + 64 * strip;
    __syncthreads();
    for (int r = 0; r < 64; ++r) tile[r][lane] = Ls[(size_t)(r0 + r) * ND + j0 + lane];
    __syncthreads();
    float b[64];
#pragma unroll
    for (int t = 0; t < 64; ++t) b[t] = tile[lane][t];
#pragma unroll
    for (int j = 0; j < 64; ++j) {
      float dj = __shfl(a[j], j, 64);
      b[j] *= (1.0f / dj);
#pragma unroll
      for (int t = j + 1; t < 64; ++t) {
        float ltj = __shfl(a[j], t, 64);
        b[t] = fmaf(-b[j], ltj, b[t]);
      }
    }
    __syncthreads();
#pragma unroll
    for (int t = 0; t < 64; ++t) tile[lane][t] = b[t];
    __syncthreads();
    for (int r = 0; r < 64; ++r) Ls[(size_t)(r0 + r) * ND + j0 + lane] = tile[r][lane];
  }
}

__global__ __launch_bounds__(256) void k_chol_update(float* __restrict__ L, int q) {
  int ti = blockIdx.x, tj = blockIdx.y, s = blockIdx.z;
  if (ti < tj) return;
  int j0 = q * 64;
  int r0 = j0 + 64 + ti * 64;
  int c0 = j0 + 64 + tj * 64;
  float* Ls = L + (size_t)s * D2;
  __shared__ float At[64][64];
  __shared__ float Bt[64][64];
  int tid = threadIdx.x;
  {
    int a = tid >> 2, km = (tid & 3) * 4;
#pragma unroll
    for (int m = 0; m < 4; ++m) {
      float4 v = *(const float4*)(Ls + (size_t)(r0 + a) * ND + j0 + km + m * 16);
      At[km + m * 16 + 0][a] = v.x;
      At[km + m * 16 + 1][a] = v.y;
      At[km + m * 16 + 2][a] = v.z;
      At[km + m * 16 + 3][a] = v.w;
      float4 w = *(const float4*)(Ls + (size_t)(c0 + a) * ND + j0 + km + m * 16);
      Bt[km + m * 16 + 0][a] = w.x;
      Bt[km + m * 16 + 1][a] = w.y;
      Bt[km + m * 16 + 2][a] = w.z;
      Bt[km + m * 16 + 3][a] = w.w;
    }
  }
  __syncthreads();
  int tx = tid & 15, ty = tid >> 4;
  float acc[4][4] = {};
#pragma unroll
  for (int k = 0; k < 64; ++k) {
    float4 a4 = *(const float4*)&At[k][ty * 4];
    float4 b4 = *(const float4*)&Bt[k][tx * 4];
    float ar[4] = {a4.x, a4.y, a4.z, a4.w};
    float br[4] = {b4.x, b4.y, b4.z, b4.w};
#pragma unroll
    for (int r = 0; r < 4; ++r)
#pragma unroll
      for (int e = 0; e < 4; ++e) acc[r][e] = fmaf(ar[r], br[e], acc[r][e]);
  }
#pragma unroll
  for (int r = 0; r < 4; ++r) {
    float* cp = Ls + (size_t)(r0 + ty * 4 + r) * ND + c0 + tx * 4;
    float4 c = *(const float4*)cp;
    c.x -= acc[r][0]; c.y -= acc[r][1]; c.z -= acc[r][2]; c.w -= acc[r][3];
    *(float4*)cp = c;
  }
}

// LT[i][j] = L[j][i] for j>=i (tiles)
__global__ __launch_bounds__(256) void k_transpose(const float* __restrict__ L,
                                                   float* __restrict__ LT) {
  int ti = blockIdx.x, tj = blockIdx.y, s = blockIdx.z;
  if (tj < ti) return;
  __shared__ float t[64][65];
  int i0 = ti * 64, j0 = tj * 64;
  const float* Ls = L + (size_t)s * D2;
  float* Ts = LT + (size_t)s * D2;
  int tx = threadIdx.x & 63, ty = threadIdx.x >> 6;
#pragma unroll
  for (int m = 0; m < 16; ++m) {
    int a = ty + 4 * m;
    t[a][tx] = Ls[(size_t)(j0 + a) * ND + i0 + tx];
  }
  __syncthreads();
#pragma unroll
  for (int m = 0; m < 16; ++m) {
    int a = ty + 4 * m;
    Ts[(size_t)(i0 + a) * ND + j0 + tx] = t[tx][a];
  }
}

// ---------------- invert the 18 diagonal 64x64 blocks (lower-tri) ----------------
__global__ __launch_bounds__(64) void k_invdiag(const float* __restrict__ L,
                                                float* __restrict__ InvD,
                                                float* __restrict__ InvDT) {
  int q = blockIdx.x, s = blockIdx.y;
  int lane = threadIdx.x;
  const float* Ls = L + (size_t)s * D2;
  __shared__ float Ds[64][65];
  __shared__ float Xls[64][64];
  for (int r = 0; r < 64; ++r)
    Ds[r][lane] = Ls[(size_t)(q * 64 + r) * ND + q * 64 + lane];
  __syncthreads();
  for (int t = 0; t < 64; ++t) {
    float sum = (t == lane) ? 1.f : 0.f;
    for (int k = 0; k < t; ++k) sum = fmaf(-Ds[t][k], Xls[k][lane], sum);
    Xls[t][lane] = sum / Ds[t][t];
  }
  __syncthreads();
  float* od = InvD + (size_t)(s * 18 + q) * 4096;
  float* ot = InvDT + (size_t)(s * 18 + q) * 4096;
  for (int t = 0; t < 64; ++t) {
    od[t * 64 + lane] = Xls[t][lane];
    ot[t * 64 + lane] = Xls[lane][t];
  }
}

// ---------------- one stage of the blocked triangular solve ----------------
template <bool FWD>
__global__ __launch_bounds__(256) void k_stage(const float* __restrict__ M,
                                               const float* __restrict__ Dinv,
                                               float* __restrict__ B,
                                               float* __restrict__ X, int q) {
  int s = blockIdx.z, ct = blockIdx.y;
  int r = FWD ? (q + blockIdx.x) : (int)blockIdx.x;
  int c0 = ct * 64;
  const float* Ms = M + (size_t)s * D2;
  const float* Dq = Dinv + (size_t)(s * 18 + q) * 4096;
  float* Bs = B + (size_t)s * ND * NCOUT;
  float* Xs = X + (size_t)s * ND * NCOUT;

  __shared__ float As[64][68];
  __shared__ float Bt[64][64];
  int tid = threadIdx.x;
  int row = tid >> 2, kq = (tid & 3) * 16;

#pragma unroll
  for (int m = 0; m < 4; ++m) {
    float4 v = *(const float4*)(Dq + row * 64 + kq + m * 4);
    As[kq + m * 4 + 0][row] = v.x;
    As[kq + m * 4 + 1][row] = v.y;
    As[kq + m * 4 + 2][row] = v.z;
    As[kq + m * 4 + 3][row] = v.w;
  }
#pragma unroll
  for (int m = 0; m < 4; ++m)
    *(float4*)&Bt[row][kq + m * 4] =
        *(const float4*)(Bs + (size_t)(q * 64 + row) * NCOUT + c0 + kq + m * 4);
  __syncthreads();

  int tx = tid & 15, ty = tid >> 4;
  float acc[4][4] = {};
#pragma unroll
  for (int k = 0; k < 64; ++k) {
    float4 a4 = *(const float4*)&As[k][ty * 4];
    float4 b4 = *(const float4*)&Bt[k][tx * 4];
    float ar[4] = {a4.x, a4.y, a4.z, a4.w};
    float br[4] = {b4.x, b4.y, b4.z, b4.w};
#pragma unroll
    for (int rr = 0; rr < 4; ++rr)
#pragma unroll
      for (int e = 0; e < 4; ++e) acc[rr][e] = fmaf(ar[rr], br[e], acc[rr][e]);
  }

  if (r == q) {
#pragma unroll
    for (int rr = 0; rr < 4; ++rr) {
      float4 v = {acc[rr][0], acc[rr][1], acc[rr][2], acc[rr][3]};
      *(float4*)(Xs + (size_t)(q * 64 + ty * 4 + rr) * NCOUT + c0 + tx * 4) = v;
    }
    return;
  }

  __syncthreads();
#pragma unroll
  for (int rr = 0; rr < 4; ++rr) {
    float4 v = {acc[rr][0], acc[rr][1], acc[rr][2], acc[rr][3]};
    *(float4*)&Bt[ty * 4 + rr][tx * 4] = v;
  }
#pragma unroll
  for (int m = 0; m < 4; ++m) {
    float4 v = *(const float4*)(Ms + (size_t)(r * 64 + row) * ND + q * 64 + kq + m * 4);
    As[kq + m * 4 + 0][row] = v.x;
    As[kq + m * 4 + 1][row] = v.y;
    As[kq + m * 4 + 2][row] = v.z;
    As[kq + m * 4 + 3][row] = v.w;
  }
  __syncthreads();

  float acc2[4][4] = {};
#pragma unroll
  for (int k = 0; k < 64; ++k) {
    float4 a4 = *(const float4*)&As[k][ty * 4];
    float4 b4 = *(const float4*)&Bt[k][tx * 4];
    float ar[4] = {a4.x, a4.y, a4.z, a4.w};
    float br[4] = {b4.x, b4.y, b4.z, b4.w};
#pragma unroll
    for (int rr = 0; rr < 4; ++rr)
#pragma unroll
      for (int e = 0; e < 4; ++e) acc2[rr][e] = fmaf(ar[rr], br[e], acc2[rr][e]);
  }
#pragma unroll
  for (int rr = 0; rr < 4; ++rr) {
    float4* p = (float4*)(Bs + (size_t)(r * 64 + ty * 4 + rr) * NCOUT + c0 + tx * 4);
    float4 c = *p;
    c.x -= acc2[rr][0]; c.y -= acc2[rr][1]; c.z -= acc2[rr][2]; c.w -= acc2[rr][3];
    *p = c;
  }
}

// T[d][c] += Z[s][c][d] (in-place on Xf) + per-sample sum(Z^2)
__global__ __launch_bounds__(256) void k_addz(float* __restrict__ Xf,
                                              const float* __restrict__ Z,
                                              float* __restrict__ pp) {
  int dt = blockIdx.x, ct = blockIdx.y, s = blockIdx.z;
  int d0 = dt * 64, c0 = ct * 64;
  __shared__ float Zt[64][68];
  int tid = threadIdx.x;
  int row = tid >> 2, kq = (tid & 3) * 16;
  float zp = 0.f;
#pragma unroll
  for (int m = 0; m < 4; ++m) {
    float4 v = *(const float4*)(Z + ((size_t)(s * NCOUT) + c0 + row) * ND + d0 + kq + m * 4);
    Zt[kq + m * 4 + 0][row] = v.x;
    Zt[kq + m * 4 + 1][row] = v.y;
    Zt[kq + m * 4 + 2][row] = v.z;
    Zt[kq + m * 4 + 3][row] = v.w;
    zp += v.x * v.x + v.y * v.y + v.z * v.z + v.w * v.w;
  }
  __syncthreads();
#pragma unroll
  for (int m = 0; m < 4; ++m) {
    float4* p = (float4*)(Xf + (size_t)(s * ND + d0 + row) * NCOUT + c0 + kq + m * 4);
    float4 x = *p;
    x.x += Zt[row][kq + m * 4 + 0];
    x.y += Zt[row][kq + m * 4 + 1];
    x.z += Zt[row][kq + m * 4 + 2];
    x.w += Zt[row][kq + m * 4 + 3];
    *p = x;
  }
#pragma unroll
  for (int m2 = 32; m2 >= 1; m2 >>= 1) zp += __shfl_xor(zp, m2, 64);
  if ((tid & 63) == 0) atomicAdd(pp + s, zp);
}

// Wm[s][c][d] = Xb[s][d][c] + per-sample sum(Wm^2)
__global__ __launch_bounds__(256) void k_writewm(const float* __restrict__ Xb,
                                                 float* __restrict__ Wm,
                                                 float* __restrict__ pp) {
  int dt = blockIdx.x, ct = blockIdx.y, s = blockIdx.z;
  int d0 = dt * 64, c0 = ct * 64;
  __shared__ float T[64][68];
  int tid = threadIdx.x;
  int row = tid >> 2, kq = (tid & 3) * 16;
  float wp = 0.f;
#pragma unroll
  for (int m = 0; m < 4; ++m) {
    float4 v = *(const float4*)(Xb + (size_t)(s * ND + d0 + row) * NCOUT + c0 + kq + m * 4);
    *(float4*)&T[row][kq + m * 4] = v;
    wp += v.x * v.x + v.y * v.y + v.z * v.z + v.w * v.w;
  }
  __syncthreads();
#pragma unroll
  for (int m = 0; m < 4; ++m) {
    float4 w;
    w.x = T[kq + m * 4 + 0][row];
    w.y = T[kq + m * 4 + 1][row];
    w.z = T[kq + m * 4 + 2][row];
    w.w = T[kq + m * 4 + 3][row];
    *(float4*)(Wm + ((size_t)(s * NCOUT) + c0 + row) * ND + d0 + kq + m * 4) = w;
  }
#pragma unroll
  for (int m2 = 32; m2 >= 1; m2 >>= 1) wp += __shfl_xor(wp, m2, 64);
  if ((tid & 63) == 0) atomicAdd(pp + 4 + s, wp);
}

__global__ __launch_bounds__(256) void k_finalize(const float* __restrict__ logd,
                                                  const float* __restrict__ pp,
                                                  float* __restrict__ out) {
  int s = blockIdx.x, tid = threadIdx.x;
  __shared__ float r0[256];
  float l = 0.f;
  for (int i = tid; i < ND; i += 256) l += logd[s * ND + i];
  r0[tid] = l;
  __syncthreads();
  for (int off = 128; off; off >>= 1) {
    if (tid < off) r0[tid] += r0[tid + off];
    __syncthreads();
  }
  if (tid == 0) {
    float logdet = 2.0f * r0[0];
    out[s] = 0.5f * (pp[s] - pp[4 + s]) - 128.0f * logdet;
  }
}

// ---------------- launcher ----------------
extern "C" void kernel_launch(void* const* d_in, const int* in_sizes, int n_in,
                              void* d_out, int out_size, void* d_ws, size_t ws_size,
                              hipStream_t stream) {
  const float* X = (const float*)d_in[0];
  const float* u = (const float*)d_in[1];
  const float* lp = (const float*)d_in[2];
  const float* Z = (const float*)d_in[3];
  float* out = (float*)d_out;

  float* ws = (float*)d_ws;
  float* sp    = ws;                                   // 64
  float* invd  = sp + 64;                              // 4608
  float* logd  = invd + (size_t)NS * ND;               // 4608
  float* pp    = logd + (size_t)NS * ND;               // 64 (8 used)
  float* InvD  = pp + 64;                              // 4*18*4096
  float* InvDT = InvD + (size_t)NS * 18 * 4096;        // 4*18*4096
  float* Xf    = InvDT + (size_t)NS * 18 * 4096;       // 4*1152*256
  float* prec  = Xf + (size_t)NS * ND * NCOUT;         // 4*1152*1152
  float* LT    = prec + (size_t)NS * D2;               // 4*1152*1152
  float* XLY   = LT + (size_t)NS * D2;                 // 4*1152*256 (reused as Xb)
  unsigned short* Phi = (unsigned short*)(XLY + (size_t)NS * ND * NCOUT);
  unsigned short* Plo = Phi + (size_t)NS * ND * NK;
  unsigned short* Yhi = Plo + (size_t)NS * ND * NK;
  unsigned short* Ylo = Yhi + (size_t)NCOUT * NK;
  float* Xb = XLY;  // safe alias: BWD never reads Xb before writing

  k_sqrtp<<<1, 64, 0, stream>>>(lp, sp, pp);
  k_patches<<<dim3(ND, NS), 256, 0, stream>>>(X, sp, Phi, Plo);
  k_ytt<<<NCOUT, 256, 0, stream>>>(u, sp, Yhi, Ylo);
  k_gemm_mfma<<<dim3(11, 9, NS), 256, 0, stream>>>(Phi, Plo, Yhi, Ylo, prec, XLY);

  for (int q = 0; q < 18; ++q) {
    k_chol_panel<<<dim3(NS, 18 - q), 64, 0, stream>>>(prec, invd, logd, q);
    if (q < 17) {
      int m = 17 - q;
      k_chol_update<<<dim3(m, m, NS), 256, 0, stream>>>(prec, q);
    }
  }
  k_transpose<<<dim3(18, 18, NS), 256, 0, stream>>>(prec, LT);
  k_invdiag<<<dim3(18, NS), 64, 0, stream>>>(prec, InvD, InvDT);

  for (int q = 0; q < 18; ++q)
    k_stage<true><<<dim3(18 - q, 4, NS), 256, 0, stream>>>(prec, InvD, XLY, Xf, q);
  k_addz<<<dim3(18, 4, NS), 256, 0, stream>>>(Xf, Z, pp);
  for (int q = 17; q >= 0; --q)
    k_stage<false><<<dim3(q + 1, 4, NS), 256, 0, stream>>>(LT, InvDT, Xf, Xb, q);

  k_writewm<<<dim3(18, 4, NS), 256, 0, stream>>>(Xb, out, pp);
  k_finalize<<<NS, 256, 0, stream>>>(logd, pp, out + (size_t)NS * NCOUT * ND);
}